// Round 11
// baseline (511.679 us; speedup 1.0000x reference)
//
#include <hip/hip_runtime.h>
#include <hip/hip_bf16.h>

#define NB 2
#define NC 16
#define NN 8192
#define NBC 32    // NB*NC columns of the skinny GEMM
#define KS 16     // fallback K-split factor
#define SROWS 16  // rows per block in staged gemm
#define SWAVES 8  // waves per block in staged gemm
#define STEP_ELEMS (NB * NN * NC)

// conv step-0 kernel geometry (proven KCH=512 shape)
#define KCH 512
#define NCHUNK (NN / KCH)     // 16
#define ROWPITCH 520          // 512 + 8 pad (1040 B rows, 16B-aligned, 2-way banks)

// steps 1..7 geometry (deeper chunks, fewer barriers)
#define KCH2 1024
#define NCHUNK2 (NN / KCH2)   // 8
#define ROWPITCH2 1032        // 2064 B rows, 16B-aligned, 2-way banks

typedef float f32x4 __attribute__((ext_vector_type(4)));
typedef __bf16 bf16x8 __attribute__((ext_vector_type(8)));

// ---------------- GroupNorm stats: one block per (b,g), 16 blocks ----------------
__global__ void gn_stats_k(const float* __restrict__ c, float* __restrict__ stats) {
    int bg = blockIdx.x;                       // b*8 + g
    const float* p = c + (size_t)bg * 16384;
    float s = 0.f, ss = 0.f;
    for (int i = threadIdx.x; i < 4096; i += 256) {
        float4 v = ((const float4*)p)[i];
        s  += v.x + v.y + v.z + v.w;
        ss += v.x*v.x + v.y*v.y + v.z*v.z + v.w*v.w;
    }
    #pragma unroll
    for (int o = 32; o; o >>= 1) { s += __shfl_down(s, o); ss += __shfl_down(ss, o); }
    __shared__ float sh[8];
    int w = threadIdx.x >> 6;
    if ((threadIdx.x & 63) == 0) { sh[w] = s; sh[w + 4] = ss; }
    __syncthreads();
    if (threadIdx.x == 0) {
        float S = sh[0]+sh[1]+sh[2]+sh[3], SS = sh[4]+sh[5]+sh[6]+sh[7];
        float mu = S * (1.f/16384.f);
        float var = SS * (1.f/16384.f) - mu*mu;
        stats[bg*2]   = mu;
        stats[bg*2+1] = rsqrtf(var + 1e-5f);
    }
}

// ---------------- y = GN(c)^T, x0 = normalize(x^T); write f32 state + bf16 X ----------------
__global__ void prep_xy_k(const float* __restrict__ x, const float* __restrict__ c,
                          const float* __restrict__ gnw, const float* __restrict__ gnb,
                          const float* __restrict__ stats,
                          float* __restrict__ y_arr, float* __restrict__ x0f,
                          __bf16* __restrict__ Xbf) {
    int tid = blockIdx.x * 256 + threadIdx.x;  // 131072 = B*N*8
    int n = tid & (NN - 1);
    int j = (tid >> 13) & 7;
    int b = tid >> 16;
    int ch0 = 2 * j;
    size_t r0 = ((size_t)(b * NC + ch0)) * NN + n;
    float c0 = c[r0], c1 = c[r0 + NN];
    float x0 = x[r0], x1 = x[r0 + NN];
    float mu = stats[(b*8 + j)*2], rstd = stats[(b*8 + j)*2 + 1];
    float y0 = (c0 - mu) * rstd * gnw[ch0]   + gnb[ch0];
    float y1 = (c1 - mu) * rstd * gnw[ch0+1] + gnb[ch0+1];
    int base = n * NBC + b * NC + ch0;
    y_arr[base] = y0; y_arr[base + 1] = y1;
    float inv = 1.f / (sqrtf(x0*x0 + x1*x1) + 1e-6f);
    x0 *= inv; x1 *= inv;
    size_t xi = ((size_t)(b * NN + n)) * NC + ch0;
    x0f[xi] = x0; x0f[xi + 1] = x1;
    Xbf[(size_t)(b*NC + ch0)     * NN + n] = (__bf16)x0;
    Xbf[(size_t)(b*NC + ch0 + 1) * NN + n] = (__bf16)x1;
}

__device__ inline bf16x8 cvt8(f32x4 s0, f32x4 s1, f32x4 w0, f32x4 w1) {
    bf16x8 r;
    r[0]=(__bf16)(s0[0]*w0[0]); r[1]=(__bf16)(s0[1]*w0[1]);
    r[2]=(__bf16)(s0[2]*w0[2]); r[3]=(__bf16)(s0[3]*w0[3]);
    r[4]=(__bf16)(s1[0]*w1[0]); r[5]=(__bf16)(s1[1]*w1[1]);
    r[6]=(__bf16)(s1[2]*w1[2]); r[7]=(__bf16)(s1[3]*w1[3]);
    return r;
}

// ---------------- step 0: coup = A @ X with A built in-flight from sc*cw, A stored for later steps ----------------
// 512 blocks x 512 threads. Per chunk: wave w reg-stages rows 2w,2w+1 of the
// NEXT chunk from sc/cw (contiguous f32x4 loads), converts after the MFMAs,
// ds_writes the LDS panel and global-stores Abf.
__global__ __launch_bounds__(512, 4) void gemm_conv_k(
    const float* __restrict__ sc, const float* __restrict__ cw,
    __bf16* __restrict__ Abf, const __bf16* __restrict__ Xc,
    float* __restrict__ coup)
{
    __shared__ __align__(16) __bf16 Abuf[2][SROWS * ROWPITCH];
    __shared__ float red[SWAVES][SROWS][36];
    int tid = threadIdx.x;
    int lane = tid & 63, w = tid >> 6;
    int mb = blockIdx.x;

    int r0 = 2 * w;
    size_t rowbase0 = (size_t)(mb * SROWS + r0) * NN;
    size_t rowbase1 = rowbase0 + NN;
    int le = lane * 8;                       // lane's 8-elem slot within a 512-chunk

    int fr = lane & 15;
    int kg = (lane >> 4) * 8;
    const __bf16* xb0 = Xc + (size_t)fr * NN + w * 64 + kg;
    const __bf16* xb1 = xb0 + (size_t)16 * NN;
    const __bf16* ab  = &Abuf[0][fr * ROWPITCH + w * 64 + kg];
    const int abstride = SROWS * ROWPITCH;

    f32x4 acc0 = {0.f,0.f,0.f,0.f}, acc1 = {0.f,0.f,0.f,0.f};

    // prologue: build chunk 0
    {
        const f32x4* sp0 = (const f32x4*)(sc + rowbase0 + le);
        const f32x4* wp0 = (const f32x4*)(cw + rowbase0 + le);
        const f32x4* sp1 = (const f32x4*)(sc + rowbase1 + le);
        const f32x4* wp1 = (const f32x4*)(cw + rowbase1 + le);
        bf16x8 o0 = cvt8(sp0[0], sp0[1], wp0[0], wp0[1]);
        bf16x8 o1 = cvt8(sp1[0], sp1[1], wp1[0], wp1[1]);
        *(bf16x8*)(&Abuf[0][r0 * ROWPITCH + le])       = o0;
        *(bf16x8*)(&Abuf[0][(r0 + 1) * ROWPITCH + le]) = o1;
        *(bf16x8*)(Abf + rowbase0 + le) = o0;
        *(bf16x8*)(Abf + rowbase1 + le) = o1;
    }
    __syncthreads();

    int buf = 0;
    for (int c = 0; c < NCHUNK; ++c) {
        bf16x8 b00 = *(const bf16x8*)(xb0 + c * KCH);
        bf16x8 b01 = *(const bf16x8*)(xb0 + c * KCH + 32);
        bf16x8 b10 = *(const bf16x8*)(xb1 + c * KCH);
        bf16x8 b11 = *(const bf16x8*)(xb1 + c * KCH + 32);
        f32x4 s0, s1, w0, w1, s2, s3, w2, w3;
        if (c + 1 < NCHUNK) {
            size_t o0 = rowbase0 + (size_t)(c + 1) * KCH + le;
            size_t o1 = rowbase1 + (size_t)(c + 1) * KCH + le;
            s0 = ((const f32x4*)(sc + o0))[0]; s1 = ((const f32x4*)(sc + o0))[1];
            w0 = ((const f32x4*)(cw + o0))[0]; w1 = ((const f32x4*)(cw + o0))[1];
            s2 = ((const f32x4*)(sc + o1))[0]; s3 = ((const f32x4*)(sc + o1))[1];
            w2 = ((const f32x4*)(cw + o1))[0]; w3 = ((const f32x4*)(cw + o1))[1];
        }
        const __bf16* ac = ab + buf * abstride;
        bf16x8 a0 = *(const bf16x8*)(ac);
        bf16x8 a1 = *(const bf16x8*)(ac + 32);
        acc0 = __builtin_amdgcn_mfma_f32_16x16x32_bf16(a0, b00, acc0, 0, 0, 0);
        acc1 = __builtin_amdgcn_mfma_f32_16x16x32_bf16(a0, b10, acc1, 0, 0, 0);
        acc0 = __builtin_amdgcn_mfma_f32_16x16x32_bf16(a1, b01, acc0, 0, 0, 0);
        acc1 = __builtin_amdgcn_mfma_f32_16x16x32_bf16(a1, b11, acc1, 0, 0, 0);
        if (c + 1 < NCHUNK) {
            int nb = buf ^ 1;
            bf16x8 o0 = cvt8(s0, s1, w0, w1);
            bf16x8 o1 = cvt8(s2, s3, w2, w3);
            *(bf16x8*)(&Abuf[nb][r0 * ROWPITCH + le])       = o0;
            *(bf16x8*)(&Abuf[nb][(r0 + 1) * ROWPITCH + le]) = o1;
            *(bf16x8*)(Abf + rowbase0 + (size_t)(c + 1) * KCH + le) = o0;
            *(bf16x8*)(Abf + rowbase1 + (size_t)(c + 1) * KCH + le) = o1;
        }
        __syncthreads();
        buf ^= 1;
    }

    // C/D layout: col = lane&15, row = (lane>>4)*4 + r  [HW-verified]
    int orow = (lane >> 4) * 4, ocol = lane & 15;
    #pragma unroll
    for (int r4 = 0; r4 < 4; ++r4) {
        red[w][orow + r4][ocol]      = acc0[r4];
        red[w][orow + r4][ocol + 16] = acc1[r4];
    }
    __syncthreads();

    if (tid < SROWS * 16) {
        int ch2 = tid & 15;
        int r_  = tid >> 4;
        float c0 = 0.f, c1 = 0.f;
        #pragma unroll
        for (int ww = 0; ww < SWAVES; ++ww) {
            c0 += red[ww][r_][2 * ch2];
            c1 += red[ww][r_][2 * ch2 + 1];
        }
        int n_ = mb * SROWS + r_;
        coup[(size_t)n_ * NBC + 2 * ch2]     = c0;
        coup[(size_t)n_ * NBC + 2 * ch2 + 1] = c1;
    }
}

// ---------------- steps 1..7: staged GEMM, KCH2=1024 (8 barriers, 4 glds/wave/chunk) ----------------
__global__ __launch_bounds__(512, 4) void gemm_stage_k(
    const __bf16* __restrict__ Abf, const __bf16* __restrict__ Xc,
    float* __restrict__ coup)
{
    __shared__ __align__(16) char smem[2 * SROWS * ROWPITCH2 * 2];  // 66 KB; red aliases after loop
    __bf16 (*Abuf)[SROWS * ROWPITCH2] = (__bf16 (*)[SROWS * ROWPITCH2])smem;
    float (*red)[SROWS][36] = (float (*)[SROWS][36])smem;
    int tid = threadIdx.x;
    int lane = tid & 63, w = tid >> 6;
    int mb = blockIdx.x;

    int r0 = 2 * w;
    const __bf16* asrc0 = Abf + (size_t)(mb * SROWS + r0) * NN + lane * 8;
    const __bf16* asrc1 = asrc0 + NN;

    int fr = lane & 15;
    int kg = (lane >> 4) * 8;
    const __bf16* xb0 = Xc + (size_t)fr * NN + w * 128 + kg;
    const __bf16* xb1 = xb0 + (size_t)16 * NN;
    const __bf16* ab  = &Abuf[0][fr * ROWPITCH2 + w * 128 + kg];
    const int abstride = SROWS * ROWPITCH2;

    f32x4 acc0 = {0.f,0.f,0.f,0.f}, acc1 = {0.f,0.f,0.f,0.f};

    // prologue: stage chunk 0 into buf 0 (2 rows x 2 KiB = 4 glds)
    #pragma unroll
    for (int h = 0; h < 2; ++h) {
        __builtin_amdgcn_global_load_lds(
            (const __attribute__((address_space(1))) void*)(asrc0 + h * 512),
            (__attribute__((address_space(3))) void*)(&Abuf[0][r0 * ROWPITCH2 + h * 512]), 16, 0, 0);
        __builtin_amdgcn_global_load_lds(
            (const __attribute__((address_space(1))) void*)(asrc1 + h * 512),
            (__attribute__((address_space(3))) void*)(&Abuf[0][(r0 + 1) * ROWPITCH2 + h * 512]), 16, 0, 0);
    }
    __syncthreads();

    int buf = 0;
    for (int c = 0; c < NCHUNK2; ++c) {
        // X fragments first (their vmcnt wait leaves staging outstanding)
        bf16x8 bx0[4], bx1[4];
        #pragma unroll
        for (int s = 0; s < 4; ++s) {
            bx0[s] = *(const bf16x8*)(xb0 + c * KCH2 + s * 32);
            bx1[s] = *(const bf16x8*)(xb1 + c * KCH2 + s * 32);
        }
        if (c + 1 < NCHUNK2) {
            int nb = buf ^ 1;
            #pragma unroll
            for (int h = 0; h < 2; ++h) {
                __builtin_amdgcn_global_load_lds(
                    (const __attribute__((address_space(1))) void*)(asrc0 + (size_t)(c + 1) * KCH2 + h * 512),
                    (__attribute__((address_space(3))) void*)(&Abuf[nb][r0 * ROWPITCH2 + h * 512]), 16, 0, 0);
                __builtin_amdgcn_global_load_lds(
                    (const __attribute__((address_space(1))) void*)(asrc1 + (size_t)(c + 1) * KCH2 + h * 512),
                    (__attribute__((address_space(3))) void*)(&Abuf[nb][(r0 + 1) * ROWPITCH2 + h * 512]), 16, 0, 0);
            }
        }
        const __bf16* ac = ab + buf * abstride;
        #pragma unroll
        for (int s = 0; s < 4; ++s) {
            bf16x8 a = *(const bf16x8*)(ac + s * 32);
            acc0 = __builtin_amdgcn_mfma_f32_16x16x32_bf16(a, bx0[s], acc0, 0, 0, 0);
            acc1 = __builtin_amdgcn_mfma_f32_16x16x32_bf16(a, bx1[s], acc1, 0, 0, 0);
        }
        __syncthreads();   // drains staging (next buf ready) + protects buf reuse
        buf ^= 1;
    }

    // C/D layout: col = lane&15, row = (lane>>4)*4 + r  [HW-verified]
    int orow = (lane >> 4) * 4, ocol = lane & 15;
    #pragma unroll
    for (int r4 = 0; r4 < 4; ++r4) {
        red[w][orow + r4][ocol]      = acc0[r4];
        red[w][orow + r4][ocol + 16] = acc1[r4];
    }
    __syncthreads();

    if (tid < SROWS * 16) {
        int ch2 = tid & 15;
        int r_  = tid >> 4;
        float c0 = 0.f, c1 = 0.f;
        #pragma unroll
        for (int ww = 0; ww < SWAVES; ++ww) {
            c0 += red[ww][r_][2 * ch2];
            c1 += red[ww][r_][2 * ch2 + 1];
        }
        int n_ = mb * SROWS + r_;
        coup[(size_t)n_ * NBC + 2 * ch2]     = c0;
        coup[(size_t)n_ * NBC + 2 * ch2 + 1] = c1;
    }
}

// ---------------- oscillator update: reads coup, updates Xbf IN PLACE (proven-safe handoff) ----------------
__global__ void update_coup_k(const float* __restrict__ coup, const float* __restrict__ y_arr,
                              const float* __restrict__ omg, const float* __restrict__ gamma,
                              float* __restrict__ x0f, __bf16* __restrict__ Xbf,
                              float* __restrict__ out_k) {
    int tid = blockIdx.x * 256 + threadIdx.x;   // 131072
    int pi = tid & 15;
    int b = pi >> 3, j = pi & 7;
    int n = tid >> 4;
    int base = n * NBC + b * NC + 2 * j;
    float c0 = coup[base];
    float c1 = coup[base + 1];
    float y0 = y_arr[base] + c0;
    float y1 = y_arr[base + 1] + c1;
    size_t xi = ((size_t)(b * NN + n)) * NC + 2 * j;
    float x0 = x0f[xi], x1 = x0f[xi + 1];
    float sim = x0 * y0 + x1 * y1;
    float p0 = y0 - sim * x0;
    float p1 = y1 - sim * x1;
    float om = fabsf(omg[j]);
    float g  = gamma[0];
    float v0 = x0 + g * ( om * x1 + p0);
    float v1 = x1 + g * (-om * x0 + p1);
    float inv = 1.f / (sqrtf(v0*v0 + v1*v1) + 1e-6f);
    v0 *= inv; v1 *= inv;
    out_k[xi] = v0; out_k[xi + 1] = v1;
    x0f[xi] = v0; x0f[xi + 1] = v1;
    Xbf[(size_t)(b*NC + 2*j)     * NN + n] = (__bf16)v0;
    Xbf[(size_t)(b*NC + 2*j + 1) * NN + n] = (__bf16)v1;
}

// ---------------- fallback path (workspace too small): fused sc*cw gemm + KS update ----------------
__device__ inline bf16x8 mulcvt8(const float* __restrict__ s, const float* __restrict__ w) {
    f32x4 s0 = ((const f32x4*)s)[0], s1 = ((const f32x4*)s)[1];
    f32x4 w0 = ((const f32x4*)w)[0], w1 = ((const f32x4*)w)[1];
    return cvt8(s0, s1, w0, w1);
}

__global__ __launch_bounds__(256) void gemm_step_fused_k(const float* __restrict__ sc,
                                                         const float* __restrict__ cw,
                                                         const __bf16* __restrict__ Xbf,
                                                         float* __restrict__ part) {
    int mb = blockIdx.x;
    int ks = blockIdx.y;
    int lane = threadIdx.x & 63;
    int w = threadIdx.x >> 6;
    int row = mb * 64 + w * 16 + (lane & 15);
    int kb  = (lane >> 4) * 8;
    int k0  = ks * (NN / KS);
    const int KC = NN / KS;
    f32x4 acc0 = {0.f,0.f,0.f,0.f}, acc1 = {0.f,0.f,0.f,0.f};
    const __bf16* bp0 = Xbf + (size_t)(lane & 15) * NN + k0 + kb;
    const __bf16* bp1 = bp0 + (size_t)16 * NN;
    const float* as = sc + (size_t)row * NN + k0 + kb;
    const float* aw = cw + (size_t)row * NN + k0 + kb;
    #pragma unroll 4
    for (int k = 0; k < KC; k += 32) {
        bf16x8 a  = mulcvt8(as + k, aw + k);
        bf16x8 b0 = *(const bf16x8*)(bp0 + k);
        bf16x8 b1 = *(const bf16x8*)(bp1 + k);
        acc0 = __builtin_amdgcn_mfma_f32_16x16x32_bf16(a, b0, acc0, 0, 0, 0);
        acc1 = __builtin_amdgcn_mfma_f32_16x16x32_bf16(a, b1, acc1, 0, 0, 0);
    }
    int orow = mb * 64 + w * 16 + (lane >> 4) * 4;
    int ocol = lane & 15;
    float* pp = part + (size_t)ks * NN * NBC + (size_t)orow * NBC + ocol;
    #pragma unroll
    for (int r = 0; r < 4; ++r) {
        pp[(size_t)r * NBC]      = acc0[r];
        pp[(size_t)r * NBC + 16] = acc1[r];
    }
}

__global__ void update_step_k(const float* __restrict__ part, const float* __restrict__ y_arr,
                              const float* __restrict__ omg, const float* __restrict__ gamma,
                              float* __restrict__ x0f, __bf16* __restrict__ Xbf,
                              float* __restrict__ out_k) {
    int tid = blockIdx.x * 256 + threadIdx.x;   // 131072
    int pi = tid & 15;
    int b = pi >> 3, j = pi & 7;
    int n = tid >> 4;
    int base = n * NBC + b * NC + 2 * j;
    float c0 = 0.f, c1 = 0.f;
    #pragma unroll
    for (int ks = 0; ks < KS; ++ks) {
        const float* p = part + (size_t)ks * NN * NBC + base;
        c0 += p[0]; c1 += p[1];
    }
    float y0 = y_arr[base] + c0;
    float y1 = y_arr[base + 1] + c1;
    size_t xi = ((size_t)(b * NN + n)) * NC + 2 * j;
    float x0 = x0f[xi], x1 = x0f[xi + 1];
    float sim = x0 * y0 + x1 * y1;
    float p0 = y0 - sim * x0;
    float p1 = y1 - sim * x1;
    float om = fabsf(omg[j]);
    float g  = gamma[0];
    float v0 = x0 + g * ( om * x1 + p0);
    float v1 = x1 + g * (-om * x0 + p1);
    float inv = 1.f / (sqrtf(v0*v0 + v1*v1) + 1e-6f);
    v0 *= inv; v1 *= inv;
    out_k[xi] = v0; out_k[xi + 1] = v1;
    x0f[xi] = v0; x0f[xi + 1] = v1;
    Xbf[(size_t)(b*NC + 2*j)     * NN + n] = (__bf16)v0;
    Xbf[(size_t)(b*NC + 2*j + 1) * NN + n] = (__bf16)v1;
}

extern "C" void kernel_launch(void* const* d_in, const int* in_sizes, int n_in,
                              void* d_out, int out_size, void* d_ws, size_t ws_size,
                              hipStream_t stream) {
    const float* x     = (const float*)d_in[0];
    const float* c     = (const float*)d_in[1];
    const float* sc    = (const float*)d_in[2];
    const float* gnw   = (const float*)d_in[3];
    const float* gnb   = (const float*)d_in[4];
    const float* cw    = (const float*)d_in[5];
    const float* omg   = (const float*)d_in[6];
    const float* gamma = (const float*)d_in[7];
    float* out = (float*)d_out;
    int Q = out_size / STEP_ELEMS;

    const size_t szA    = (size_t)NN * NN * 2;        // 128 MiB
    const size_t szX    = (size_t)NBC * NN * 2;       // 512 KiB
    const size_t szX0f  = (size_t)NB * NN * NC * 4;   // 1 MiB
    const size_t szY    = (size_t)NN * NBC * 4;       // 1 MiB
    const size_t szCoup = (size_t)NN * NBC * 4;       // 1 MiB
    const size_t szPart = (size_t)KS * NN * NBC * 4;  // 16 MiB (fallback only)
    const size_t rest = szX + szX0f + szY + szCoup + szPart + 256;
    bool bigws = ws_size >= szA + rest;

    char* p = (char*)d_ws;
    __bf16* Abf = nullptr;
    if (bigws) { Abf = (__bf16*)p; p += szA; }
    __bf16* Xbf  = (__bf16*)p; p += szX;
    float* x0f   = (float*)p;  p += szX0f;
    float* y_arr = (float*)p;  p += szY;
    float* coup  = (float*)p;  p += szCoup;
    float* part  = (float*)p;  p += szPart;
    float* stats = (float*)p;  p += 256;

    gn_stats_k<<<16, 256, 0, stream>>>(c, stats);
    prep_xy_k<<<(NB * NN * 8) / 256, 256, 0, stream>>>(x, c, gnw, gnb, stats, y_arr, x0f, Xbf);

    if (bigws) {
        for (int q = 0; q < Q; ++q) {
            if (q == 0)
                gemm_conv_k<<<NN / SROWS, SWAVES * 64, 0, stream>>>(sc, cw, Abf, Xbf, coup);
            else
                gemm_stage_k<<<NN / SROWS, SWAVES * 64, 0, stream>>>(Abf, Xbf, coup);
            update_coup_k<<<(NB * NN * 8) / 256, 256, 0, stream>>>(
                coup, y_arr, omg, gamma, x0f, Xbf, out + (size_t)q * STEP_ELEMS);
        }
    } else {
        dim3 gg(NN / 64, KS);
        for (int q = 0; q < Q; ++q) {
            gemm_step_fused_k<<<gg, 256, 0, stream>>>(sc, cw, Xbf, part);
            update_step_k<<<(NB * NN * 8) / 256, 256, 0, stream>>>(
                part, y_arr, omg, gamma, x0f, Xbf, out + (size_t)q * STEP_ELEMS);
        }
    }
}

// Round 12
// 459.810 us; speedup vs baseline: 1.1128x; 1.1128x over previous
//
#include <hip/hip_runtime.h>
#include <hip/hip_bf16.h>

#define NB 2
#define NC 16
#define NN 8192
#define NBC 32    // NB*NC columns of the skinny GEMM
#define KS 16     // fallback K-split factor
#define SROWS 16  // rows per block in step gemm
#define SWAVES 8  // waves per block in step gemm
#define STEP_ELEMS (NB * NN * NC)

typedef float f32x4 __attribute__((ext_vector_type(4)));
typedef __bf16 bf16x8 __attribute__((ext_vector_type(8)));

// ---------------- GroupNorm stats: one block per (b,g), 16 blocks ----------------
__global__ void gn_stats_k(const float* __restrict__ c, float* __restrict__ stats) {
    int bg = blockIdx.x;                       // b*8 + g
    const float* p = c + (size_t)bg * 16384;
    float s = 0.f, ss = 0.f;
    for (int i = threadIdx.x; i < 4096; i += 256) {
        float4 v = ((const float4*)p)[i];
        s  += v.x + v.y + v.z + v.w;
        ss += v.x*v.x + v.y*v.y + v.z*v.z + v.w*v.w;
    }
    #pragma unroll
    for (int o = 32; o; o >>= 1) { s += __shfl_down(s, o); ss += __shfl_down(ss, o); }
    __shared__ float sh[8];
    int w = threadIdx.x >> 6;
    if ((threadIdx.x & 63) == 0) { sh[w] = s; sh[w + 4] = ss; }
    __syncthreads();
    if (threadIdx.x == 0) {
        float S = sh[0]+sh[1]+sh[2]+sh[3], SS = sh[4]+sh[5]+sh[6]+sh[7];
        float mu = S * (1.f/16384.f);
        float var = SS * (1.f/16384.f) - mu*mu;
        stats[bg*2]   = mu;
        stats[bg*2+1] = rsqrtf(var + 1e-5f);
    }
}

// ---------------- y = GN(c)^T, x0 = normalize(x^T); write f32 state + bf16 X ----------------
__global__ void prep_xy_k(const float* __restrict__ x, const float* __restrict__ c,
                          const float* __restrict__ gnw, const float* __restrict__ gnb,
                          const float* __restrict__ stats,
                          float* __restrict__ y_arr, float* __restrict__ x0f,
                          __bf16* __restrict__ Xbf) {
    int tid = blockIdx.x * 256 + threadIdx.x;  // 131072 = B*N*8
    int n = tid & (NN - 1);
    int j = (tid >> 13) & 7;
    int b = tid >> 16;
    int ch0 = 2 * j;
    size_t r0 = ((size_t)(b * NC + ch0)) * NN + n;
    float c0 = c[r0], c1 = c[r0 + NN];
    float x0 = x[r0], x1 = x[r0 + NN];
    float mu = stats[(b*8 + j)*2], rstd = stats[(b*8 + j)*2 + 1];
    float y0 = (c0 - mu) * rstd * gnw[ch0]   + gnb[ch0];
    float y1 = (c1 - mu) * rstd * gnw[ch0+1] + gnb[ch0+1];
    int base = n * NBC + b * NC + ch0;
    y_arr[base] = y0; y_arr[base + 1] = y1;
    float inv = 1.f / (sqrtf(x0*x0 + x1*x1) + 1e-6f);
    x0 *= inv; x1 *= inv;
    size_t xi = ((size_t)(b * NN + n)) * NC + ch0;
    x0f[xi] = x0; x0f[xi + 1] = x1;
    Xbf[(size_t)(b*NC + ch0)     * NN + n] = (__bf16)x0;
    Xbf[(size_t)(b*NC + ch0 + 1) * NN + n] = (__bf16)x1;
}

__device__ inline bf16x8 cvt8(f32x4 s0, f32x4 s1, f32x4 w0, f32x4 w1) {
    bf16x8 r;
    r[0]=(__bf16)(s0[0]*w0[0]); r[1]=(__bf16)(s0[1]*w0[1]);
    r[2]=(__bf16)(s0[2]*w0[2]); r[3]=(__bf16)(s0[3]*w0[3]);
    r[4]=(__bf16)(s1[0]*w1[0]); r[5]=(__bf16)(s1[1]*w1[1]);
    r[6]=(__bf16)(s1[2]*w1[2]); r[7]=(__bf16)(s1[3]*w1[3]);
    return r;
}

// ---------------- A = bf16(sc*cw) stored in MFMA-fragment order ----------------
// Fragment slot (p, k32) = 1 KiB: lane l (= row + oct*16) x 8 elems, covering
// rows [p*16,+16), k [k32*32,+32). Block (p, kc) does 16 rows x 512 k via LDS
// transpose: coalesced row-major reads -> LDS -> contiguous 16 KiB write.
__global__ __launch_bounds__(256) void prep_A_frag_k(const float* __restrict__ sc,
                                                     const float* __restrict__ cw,
                                                     __bf16* __restrict__ Af) {
    __shared__ __align__(16) __bf16 tb[16][520];   // 16 slots, pitch 1040 B
    int t = threadIdx.x;
    int p  = blockIdx.x >> 4;
    int kc = blockIdx.x & 15;
    // phase 1: read + convert + LDS (fragment position)
    #pragma unroll
    for (int it = 0; it < 4; ++it) {
        int e = it * 2048 + t * 8;       // 0..8191
        int row = e >> 9;                // 0..15
        int kloc = e & 511;
        size_t src = (size_t)(p * 16 + row) * NN + kc * 512 + kloc;
        f32x4 s0 = ((const f32x4*)(sc + src))[0], s1 = ((const f32x4*)(sc + src))[1];
        f32x4 w0 = ((const f32x4*)(cw + src))[0], w1 = ((const f32x4*)(cw + src))[1];
        bf16x8 o = cvt8(s0, s1, w0, w1);
        int k32 = kloc >> 5;
        int lane_f = row + (((kloc & 31) >> 3) << 4);
        *(bf16x8*)(&tb[k32][lane_f * 8]) = o;
    }
    __syncthreads();
    // phase 2: LDS -> contiguous global (fragment order)
    size_t obase = ((size_t)p * 256 + kc * 16) * 512;
    #pragma unroll
    for (int it = 0; it < 4; ++it) {
        int f = it * 256 + t;            // 16B-slot index, 0..1023
        int k32 = f >> 6;
        int lf  = f & 63;
        bf16x8 v = *(const bf16x8*)(&tb[k32][lf * 8]);
        *(bf16x8*)(Af + obase + (size_t)f * 8) = v;
    }
}

// ---------------- step GEMM: coup = A @ X, A read as contiguous fragment stream ----------------
// 512 blocks x 512 threads. Wave w: k32 slots [w*32, +32) of panel mb —
// a per-wave contiguous 32 KiB stream. No LDS, no K-loop barriers.
__global__ __launch_bounds__(512, 4) void gemm_frag_k(
    const __bf16* __restrict__ Af, const __bf16* __restrict__ Xc,
    float* __restrict__ coup)
{
    __shared__ float red[SWAVES][SROWS][36];
    int tid = threadIdx.x;
    int lane = tid & 63, w = tid >> 6;
    int mb = blockIdx.x;

    const __bf16* ap = Af + ((size_t)mb * 256 + w * 32) * 512 + lane * 8;
    int fr = lane & 15;
    int kg = (lane >> 4) * 8;
    const __bf16* xb0 = Xc + (size_t)fr * NN + w * 1024 + kg;
    const __bf16* xb1 = xb0 + (size_t)16 * NN;

    f32x4 acc0 = {0.f,0.f,0.f,0.f}, acc1 = {0.f,0.f,0.f,0.f};

    // depth-2 rotation over 16 iterations of 64 k (2 slots each)
    bf16x8 a0  = *(const bf16x8*)(ap);
    bf16x8 a1  = *(const bf16x8*)(ap + 512);
    bf16x8 b00 = *(const bf16x8*)(xb0);
    bf16x8 b01 = *(const bf16x8*)(xb0 + 32);
    bf16x8 b10 = *(const bf16x8*)(xb1);
    bf16x8 b11 = *(const bf16x8*)(xb1 + 32);
    #pragma unroll
    for (int it = 0; it < 15; ++it) {
        bf16x8 na0  = *(const bf16x8*)(ap  + (2 * it + 2) * 512);
        bf16x8 na1  = *(const bf16x8*)(ap  + (2 * it + 3) * 512);
        bf16x8 nb00 = *(const bf16x8*)(xb0 + it * 64 + 64);
        bf16x8 nb01 = *(const bf16x8*)(xb0 + it * 64 + 96);
        bf16x8 nb10 = *(const bf16x8*)(xb1 + it * 64 + 64);
        bf16x8 nb11 = *(const bf16x8*)(xb1 + it * 64 + 96);
        acc0 = __builtin_amdgcn_mfma_f32_16x16x32_bf16(a0, b00, acc0, 0, 0, 0);
        acc1 = __builtin_amdgcn_mfma_f32_16x16x32_bf16(a0, b10, acc1, 0, 0, 0);
        acc0 = __builtin_amdgcn_mfma_f32_16x16x32_bf16(a1, b01, acc0, 0, 0, 0);
        acc1 = __builtin_amdgcn_mfma_f32_16x16x32_bf16(a1, b11, acc1, 0, 0, 0);
        a0 = na0; a1 = na1; b00 = nb00; b01 = nb01; b10 = nb10; b11 = nb11;
    }
    acc0 = __builtin_amdgcn_mfma_f32_16x16x32_bf16(a0, b00, acc0, 0, 0, 0);
    acc1 = __builtin_amdgcn_mfma_f32_16x16x32_bf16(a0, b10, acc1, 0, 0, 0);
    acc0 = __builtin_amdgcn_mfma_f32_16x16x32_bf16(a1, b01, acc0, 0, 0, 0);
    acc1 = __builtin_amdgcn_mfma_f32_16x16x32_bf16(a1, b11, acc1, 0, 0, 0);

    // C/D layout: col = lane&15, row = (lane>>4)*4 + r  [HW-verified]
    int orow = (lane >> 4) * 4, ocol = lane & 15;
    #pragma unroll
    for (int r4 = 0; r4 < 4; ++r4) {
        red[w][orow + r4][ocol]      = acc0[r4];
        red[w][orow + r4][ocol + 16] = acc1[r4];
    }
    __syncthreads();

    if (tid < SROWS * 16) {
        int ch2 = tid & 15;
        int r_  = tid >> 4;
        float c0 = 0.f, c1 = 0.f;
        #pragma unroll
        for (int ww = 0; ww < SWAVES; ++ww) {
            c0 += red[ww][r_][2 * ch2];
            c1 += red[ww][r_][2 * ch2 + 1];
        }
        int n_ = mb * SROWS + r_;
        coup[(size_t)n_ * NBC + 2 * ch2]     = c0;
        coup[(size_t)n_ * NBC + 2 * ch2 + 1] = c1;
    }
}

// ---------------- oscillator update: reads coup, updates Xbf IN PLACE (proven-safe handoff) ----------------
__global__ void update_coup_k(const float* __restrict__ coup, const float* __restrict__ y_arr,
                              const float* __restrict__ omg, const float* __restrict__ gamma,
                              float* __restrict__ x0f, __bf16* __restrict__ Xbf,
                              float* __restrict__ out_k) {
    int tid = blockIdx.x * 256 + threadIdx.x;   // 131072
    int pi = tid & 15;
    int b = pi >> 3, j = pi & 7;
    int n = tid >> 4;
    int base = n * NBC + b * NC + 2 * j;
    float c0 = coup[base];
    float c1 = coup[base + 1];
    float y0 = y_arr[base] + c0;
    float y1 = y_arr[base + 1] + c1;
    size_t xi = ((size_t)(b * NN + n)) * NC + 2 * j;
    float x0 = x0f[xi], x1 = x0f[xi + 1];
    float sim = x0 * y0 + x1 * y1;
    float p0 = y0 - sim * x0;
    float p1 = y1 - sim * x1;
    float om = fabsf(omg[j]);
    float g  = gamma[0];
    float v0 = x0 + g * ( om * x1 + p0);
    float v1 = x1 + g * (-om * x0 + p1);
    float inv = 1.f / (sqrtf(v0*v0 + v1*v1) + 1e-6f);
    v0 *= inv; v1 *= inv;
    out_k[xi] = v0; out_k[xi + 1] = v1;
    x0f[xi] = v0; x0f[xi + 1] = v1;
    Xbf[(size_t)(b*NC + 2*j)     * NN + n] = (__bf16)v0;
    Xbf[(size_t)(b*NC + 2*j + 1) * NN + n] = (__bf16)v1;
}

// ---------------- fallback path (workspace too small): fused sc*cw gemm + KS update ----------------
__device__ inline bf16x8 mulcvt8(const float* __restrict__ s, const float* __restrict__ w) {
    f32x4 s0 = ((const f32x4*)s)[0], s1 = ((const f32x4*)s)[1];
    f32x4 w0 = ((const f32x4*)w)[0], w1 = ((const f32x4*)w)[1];
    return cvt8(s0, s1, w0, w1);
}

__global__ __launch_bounds__(256) void gemm_step_fused_k(const float* __restrict__ sc,
                                                         const float* __restrict__ cw,
                                                         const __bf16* __restrict__ Xbf,
                                                         float* __restrict__ part) {
    int mb = blockIdx.x;
    int ks = blockIdx.y;
    int lane = threadIdx.x & 63;
    int w = threadIdx.x >> 6;
    int row = mb * 64 + w * 16 + (lane & 15);
    int kb  = (lane >> 4) * 8;
    int k0  = ks * (NN / KS);
    const int KC = NN / KS;
    f32x4 acc0 = {0.f,0.f,0.f,0.f}, acc1 = {0.f,0.f,0.f,0.f};
    const __bf16* bp0 = Xbf + (size_t)(lane & 15) * NN + k0 + kb;
    const __bf16* bp1 = bp0 + (size_t)16 * NN;
    const float* as = sc + (size_t)row * NN + k0 + kb;
    const float* aw = cw + (size_t)row * NN + k0 + kb;
    #pragma unroll 4
    for (int k = 0; k < KC; k += 32) {
        bf16x8 a  = mulcvt8(as + k, aw + k);
        bf16x8 b0 = *(const bf16x8*)(bp0 + k);
        bf16x8 b1 = *(const bf16x8*)(bp1 + k);
        acc0 = __builtin_amdgcn_mfma_f32_16x16x32_bf16(a, b0, acc0, 0, 0, 0);
        acc1 = __builtin_amdgcn_mfma_f32_16x16x32_bf16(a, b1, acc1, 0, 0, 0);
    }
    int orow = mb * 64 + w * 16 + (lane >> 4) * 4;
    int ocol = lane & 15;
    float* pp = part + (size_t)ks * NN * NBC + (size_t)orow * NBC + ocol;
    #pragma unroll
    for (int r = 0; r < 4; ++r) {
        pp[(size_t)r * NBC]      = acc0[r];
        pp[(size_t)r * NBC + 16] = acc1[r];
    }
}

__global__ void update_step_k(const float* __restrict__ part, const float* __restrict__ y_arr,
                              const float* __restrict__ omg, const float* __restrict__ gamma,
                              float* __restrict__ x0f, __bf16* __restrict__ Xbf,
                              float* __restrict__ out_k) {
    int tid = blockIdx.x * 256 + threadIdx.x;   // 131072
    int pi = tid & 15;
    int b = pi >> 3, j = pi & 7;
    int n = tid >> 4;
    int base = n * NBC + b * NC + 2 * j;
    float c0 = 0.f, c1 = 0.f;
    #pragma unroll
    for (int ks = 0; ks < KS; ++ks) {
        const float* p = part + (size_t)ks * NN * NBC + base;
        c0 += p[0]; c1 += p[1];
    }
    float y0 = y_arr[base] + c0;
    float y1 = y_arr[base + 1] + c1;
    size_t xi = ((size_t)(b * NN + n)) * NC + 2 * j;
    float x0 = x0f[xi], x1 = x0f[xi + 1];
    float sim = x0 * y0 + x1 * y1;
    float p0 = y0 - sim * x0;
    float p1 = y1 - sim * x1;
    float om = fabsf(omg[j]);
    float g  = gamma[0];
    float v0 = x0 + g * ( om * x1 + p0);
    float v1 = x1 + g * (-om * x0 + p1);
    float inv = 1.f / (sqrtf(v0*v0 + v1*v1) + 1e-6f);
    v0 *= inv; v1 *= inv;
    out_k[xi] = v0; out_k[xi + 1] = v1;
    x0f[xi] = v0; x0f[xi + 1] = v1;
    Xbf[(size_t)(b*NC + 2*j)     * NN + n] = (__bf16)v0;
    Xbf[(size_t)(b*NC + 2*j + 1) * NN + n] = (__bf16)v1;
}

extern "C" void kernel_launch(void* const* d_in, const int* in_sizes, int n_in,
                              void* d_out, int out_size, void* d_ws, size_t ws_size,
                              hipStream_t stream) {
    const float* x     = (const float*)d_in[0];
    const float* c     = (const float*)d_in[1];
    const float* sc    = (const float*)d_in[2];
    const float* gnw   = (const float*)d_in[3];
    const float* gnb   = (const float*)d_in[4];
    const float* cw    = (const float*)d_in[5];
    const float* omg   = (const float*)d_in[6];
    const float* gamma = (const float*)d_in[7];
    float* out = (float*)d_out;
    int Q = out_size / STEP_ELEMS;

    const size_t szA    = (size_t)NN * NN * 2;        // 128 MiB
    const size_t szX    = (size_t)NBC * NN * 2;       // 512 KiB
    const size_t szX0f  = (size_t)NB * NN * NC * 4;   // 1 MiB
    const size_t szY    = (size_t)NN * NBC * 4;       // 1 MiB
    const size_t szCoup = (size_t)NN * NBC * 4;       // 1 MiB
    const size_t szPart = (size_t)KS * NN * NBC * 4;  // 16 MiB (fallback only)
    const size_t rest = szX + szX0f + szY + szCoup + szPart + 256;
    bool bigws = ws_size >= szA + rest;

    char* p = (char*)d_ws;
    __bf16* Af = nullptr;
    if (bigws) { Af = (__bf16*)p; p += szA; }
    __bf16* Xbf  = (__bf16*)p; p += szX;
    float* x0f   = (float*)p;  p += szX0f;
    float* y_arr = (float*)p;  p += szY;
    float* coup  = (float*)p;  p += szCoup;
    float* part  = (float*)p;  p += szPart;
    float* stats = (float*)p;  p += 256;

    gn_stats_k<<<16, 256, 0, stream>>>(c, stats);
    prep_xy_k<<<(NB * NN * 8) / 256, 256, 0, stream>>>(x, c, gnw, gnb, stats, y_arr, x0f, Xbf);

    if (bigws) {
        prep_A_frag_k<<<(NN / 16) * (NN / 512), 256, 0, stream>>>(sc, cw, Af);
        for (int q = 0; q < Q; ++q) {
            gemm_frag_k<<<NN / SROWS, SWAVES * 64, 0, stream>>>(Af, Xbf, coup);
            update_coup_k<<<(NB * NN * 8) / 256, 256, 0, stream>>>(
                coup, y_arr, omg, gamma, x0f, Xbf, out + (size_t)q * STEP_ELEMS);
        }
    } else {
        dim3 gg(NN / 64, KS);
        for (int q = 0; q < Q; ++q) {
            gemm_step_fused_k<<<gg, 256, 0, stream>>>(sc, cw, Xbf, part);
            update_step_k<<<(NB * NN * 8) / 256, 256, 0, stream>>>(
                part, y_arr, omg, gamma, x0f, Xbf, out + (size_t)q * STEP_ELEMS);
        }
    }
}

// Round 13
// 397.049 us; speedup vs baseline: 1.2887x; 1.1581x over previous
//
#include <hip/hip_runtime.h>
#include <hip/hip_bf16.h>

#define NB 2
#define NC 16
#define NN 8192
#define NBC 32    // NB*NC columns of the skinny GEMM
#define KS 16     // fallback K-split factor
#define STEP_ELEMS (NB * NN * NC)

typedef float f32x4 __attribute__((ext_vector_type(4)));
typedef __bf16 bf16x8 __attribute__((ext_vector_type(8)));

// ---------------- GroupNorm stats: one block per (b,g), 16 blocks ----------------
__global__ void gn_stats_k(const float* __restrict__ c, float* __restrict__ stats) {
    int bg = blockIdx.x;                       // b*8 + g
    const float* p = c + (size_t)bg * 16384;
    float s = 0.f, ss = 0.f;
    for (int i = threadIdx.x; i < 4096; i += 256) {
        float4 v = ((const float4*)p)[i];
        s  += v.x + v.y + v.z + v.w;
        ss += v.x*v.x + v.y*v.y + v.z*v.z + v.w*v.w;
    }
    #pragma unroll
    for (int o = 32; o; o >>= 1) { s += __shfl_down(s, o); ss += __shfl_down(ss, o); }
    __shared__ float sh[8];
    int w = threadIdx.x >> 6;
    if ((threadIdx.x & 63) == 0) { sh[w] = s; sh[w + 4] = ss; }
    __syncthreads();
    if (threadIdx.x == 0) {
        float S = sh[0]+sh[1]+sh[2]+sh[3], SS = sh[4]+sh[5]+sh[6]+sh[7];
        float mu = S * (1.f/16384.f);
        float var = SS * (1.f/16384.f) - mu*mu;
        stats[bg*2]   = mu;
        stats[bg*2+1] = rsqrtf(var + 1e-5f);
    }
}

// ---------------- y = GN(c)^T, x0 = normalize(x^T); write f32 state + bf16 X ----------------
__global__ void prep_xy_k(const float* __restrict__ x, const float* __restrict__ c,
                          const float* __restrict__ gnw, const float* __restrict__ gnb,
                          const float* __restrict__ stats,
                          float* __restrict__ y_arr, float* __restrict__ x0f,
                          __bf16* __restrict__ Xbf) {
    int tid = blockIdx.x * 256 + threadIdx.x;  // 131072 = B*N*8
    int n = tid & (NN - 1);
    int j = (tid >> 13) & 7;
    int b = tid >> 16;
    int ch0 = 2 * j;
    size_t r0 = ((size_t)(b * NC + ch0)) * NN + n;
    float c0 = c[r0], c1 = c[r0 + NN];
    float x0 = x[r0], x1 = x[r0 + NN];
    float mu = stats[(b*8 + j)*2], rstd = stats[(b*8 + j)*2 + 1];
    float y0 = (c0 - mu) * rstd * gnw[ch0]   + gnb[ch0];
    float y1 = (c1 - mu) * rstd * gnw[ch0+1] + gnb[ch0+1];
    int base = n * NBC + b * NC + ch0;
    y_arr[base] = y0; y_arr[base + 1] = y1;
    float inv = 1.f / (sqrtf(x0*x0 + x1*x1) + 1e-6f);
    x0 *= inv; x1 *= inv;
    size_t xi = ((size_t)(b * NN + n)) * NC + ch0;
    x0f[xi] = x0; x0f[xi + 1] = x1;
    Xbf[(size_t)(b*NC + ch0)     * NN + n] = (__bf16)x0;
    Xbf[(size_t)(b*NC + ch0 + 1) * NN + n] = (__bf16)x1;
}

__device__ inline bf16x8 cvt8(f32x4 s0, f32x4 s1, f32x4 w0, f32x4 w1) {
    bf16x8 r;
    r[0]=(__bf16)(s0[0]*w0[0]); r[1]=(__bf16)(s0[1]*w0[1]);
    r[2]=(__bf16)(s0[2]*w0[2]); r[3]=(__bf16)(s0[3]*w0[3]);
    r[4]=(__bf16)(s1[0]*w1[0]); r[5]=(__bf16)(s1[1]*w1[1]);
    r[6]=(__bf16)(s1[2]*w1[2]); r[7]=(__bf16)(s1[3]*w1[3]);
    return r;
}

// ---------------- A = bf16(sc*cw) in MFMA-fragment order; skewed LDS (no bank conflicts) ----------------
// Fragment slot (p, k32) = 1 KiB: lane l (= row + oct*16) x 8 elems. Block (p,kc)
// does 16 rows x 512 k. LDS tb[k32][oct][17-pad row][8]: oct stride 272 B -> +4 banks.
__global__ __launch_bounds__(256, 6) void prep_A_frag_k(const float* __restrict__ sc,
                                                        const float* __restrict__ cw,
                                                        __bf16* __restrict__ Af) {
    __shared__ __align__(16) __bf16 tb[16][4][17][8];
    int t = threadIdx.x;
    int p  = blockIdx.x >> 4;
    int kc = blockIdx.x & 15;
    // phase 1: read + convert + LDS, grouped 2 iterations deep (8 x f32x4 in flight)
    #pragma unroll
    for (int h = 0; h < 2; ++h) {
        f32x4 s[4], wv[4];
        int e0 = (2*h) * 2048 + t * 8;
        int e1 = (2*h + 1) * 2048 + t * 8;
        size_t src0 = (size_t)(p * 16 + (e0 >> 9)) * NN + kc * 512 + (e0 & 511);
        size_t src1 = (size_t)(p * 16 + (e1 >> 9)) * NN + kc * 512 + (e1 & 511);
        s[0] = ((const f32x4*)(sc + src0))[0]; s[1] = ((const f32x4*)(sc + src0))[1];
        s[2] = ((const f32x4*)(sc + src1))[0]; s[3] = ((const f32x4*)(sc + src1))[1];
        wv[0] = ((const f32x4*)(cw + src0))[0]; wv[1] = ((const f32x4*)(cw + src0))[1];
        wv[2] = ((const f32x4*)(cw + src1))[0]; wv[3] = ((const f32x4*)(cw + src1))[1];
        bf16x8 o0 = cvt8(s[0], s[1], wv[0], wv[1]);
        bf16x8 o1 = cvt8(s[2], s[3], wv[2], wv[3]);
        int k0 = (e0 & 511) >> 5, oc0 = ((e0 & 31) >> 3), r0 = e0 >> 9;
        int k1 = (e1 & 511) >> 5, oc1 = ((e1 & 31) >> 3), r1 = e1 >> 9;
        *(bf16x8*)(&tb[k0][oc0][r0][0]) = o0;
        *(bf16x8*)(&tb[k1][oc1][r1][0]) = o1;
    }
    __syncthreads();
    // phase 2: LDS -> contiguous global (fragment order)
    size_t obase = ((size_t)p * 256 + kc * 16) * 512;
    #pragma unroll
    for (int it = 0; it < 4; ++it) {
        int f = it * 256 + t;            // 16B-slot index, 0..1023
        int k32 = f >> 6;
        int lf  = f & 63;
        bf16x8 v = *(const bf16x8*)(&tb[k32][lf >> 4][lf & 15][0]);
        *(bf16x8*)(Af + obase + (size_t)f * 8) = v;
    }
}

// ---------------- step GEMM: coup = A @ X, 32 rows (2 panels) per block ----------------
// 256 blocks x 1024 threads (16 waves, 4/SIMD). Wave w: k-slice [w*512,+512) of
// both panels — contiguous 16 KiB A streams; X fragments reused across panels.
__global__ __launch_bounds__(1024, 4) void gemm_frag_k(
    const __bf16* __restrict__ Af, const __bf16* __restrict__ Xc,
    float* __restrict__ coup)
{
    __shared__ float red[16][32][36];
    int tid = threadIdx.x;
    int lane = tid & 63, w = tid >> 6;   // w 0..15
    int mb = blockIdx.x;                 // 0..255

    const __bf16* ap0 = Af + ((size_t)(2 * mb)     * 256 + w * 16) * 512 + lane * 8;
    const __bf16* ap1 = Af + ((size_t)(2 * mb + 1) * 256 + w * 16) * 512 + lane * 8;
    int fr = lane & 15;
    int kg = (lane >> 4) * 8;
    const __bf16* xb0 = Xc + (size_t)fr * NN + w * 512 + kg;
    const __bf16* xb1 = xb0 + (size_t)16 * NN;

    f32x4 acc00 = {0.f,0.f,0.f,0.f}, acc01 = {0.f,0.f,0.f,0.f};
    f32x4 acc10 = {0.f,0.f,0.f,0.f}, acc11 = {0.f,0.f,0.f,0.f};

    // depth-2 rotation over 8 iterations of 64 k (2 slots per panel)
    bf16x8 a00 = *(const bf16x8*)(ap0);
    bf16x8 a01 = *(const bf16x8*)(ap0 + 512);
    bf16x8 a10 = *(const bf16x8*)(ap1);
    bf16x8 a11 = *(const bf16x8*)(ap1 + 512);
    bf16x8 b00 = *(const bf16x8*)(xb0);
    bf16x8 b01 = *(const bf16x8*)(xb0 + 32);
    bf16x8 b10 = *(const bf16x8*)(xb1);
    bf16x8 b11 = *(const bf16x8*)(xb1 + 32);
    #pragma unroll
    for (int it = 0; it < 7; ++it) {
        bf16x8 na00 = *(const bf16x8*)(ap0 + (2 * it + 2) * 512);
        bf16x8 na01 = *(const bf16x8*)(ap0 + (2 * it + 3) * 512);
        bf16x8 na10 = *(const bf16x8*)(ap1 + (2 * it + 2) * 512);
        bf16x8 na11 = *(const bf16x8*)(ap1 + (2 * it + 3) * 512);
        bf16x8 nb00 = *(const bf16x8*)(xb0 + it * 64 + 64);
        bf16x8 nb01 = *(const bf16x8*)(xb0 + it * 64 + 96);
        bf16x8 nb10 = *(const bf16x8*)(xb1 + it * 64 + 64);
        bf16x8 nb11 = *(const bf16x8*)(xb1 + it * 64 + 96);
        acc00 = __builtin_amdgcn_mfma_f32_16x16x32_bf16(a00, b00, acc00, 0, 0, 0);
        acc01 = __builtin_amdgcn_mfma_f32_16x16x32_bf16(a00, b10, acc01, 0, 0, 0);
        acc10 = __builtin_amdgcn_mfma_f32_16x16x32_bf16(a10, b00, acc10, 0, 0, 0);
        acc11 = __builtin_amdgcn_mfma_f32_16x16x32_bf16(a10, b10, acc11, 0, 0, 0);
        acc00 = __builtin_amdgcn_mfma_f32_16x16x32_bf16(a01, b01, acc00, 0, 0, 0);
        acc01 = __builtin_amdgcn_mfma_f32_16x16x32_bf16(a01, b11, acc01, 0, 0, 0);
        acc10 = __builtin_amdgcn_mfma_f32_16x16x32_bf16(a11, b01, acc10, 0, 0, 0);
        acc11 = __builtin_amdgcn_mfma_f32_16x16x32_bf16(a11, b11, acc11, 0, 0, 0);
        a00 = na00; a01 = na01; a10 = na10; a11 = na11;
        b00 = nb00; b01 = nb01; b10 = nb10; b11 = nb11;
    }
    acc00 = __builtin_amdgcn_mfma_f32_16x16x32_bf16(a00, b00, acc00, 0, 0, 0);
    acc01 = __builtin_amdgcn_mfma_f32_16x16x32_bf16(a00, b10, acc01, 0, 0, 0);
    acc10 = __builtin_amdgcn_mfma_f32_16x16x32_bf16(a10, b00, acc10, 0, 0, 0);
    acc11 = __builtin_amdgcn_mfma_f32_16x16x32_bf16(a10, b10, acc11, 0, 0, 0);
    acc00 = __builtin_amdgcn_mfma_f32_16x16x32_bf16(a01, b01, acc00, 0, 0, 0);
    acc01 = __builtin_amdgcn_mfma_f32_16x16x32_bf16(a01, b11, acc01, 0, 0, 0);
    acc10 = __builtin_amdgcn_mfma_f32_16x16x32_bf16(a11, b01, acc10, 0, 0, 0);
    acc11 = __builtin_amdgcn_mfma_f32_16x16x32_bf16(a11, b11, acc11, 0, 0, 0);

    // C/D layout: col = lane&15, row = (lane>>4)*4 + r  [HW-verified]
    int orow = (lane >> 4) * 4, ocol = lane & 15;
    #pragma unroll
    for (int r4 = 0; r4 < 4; ++r4) {
        red[w][orow + r4][ocol]           = acc00[r4];
        red[w][orow + r4][ocol + 16]      = acc01[r4];
        red[w][16 + orow + r4][ocol]      = acc10[r4];
        red[w][16 + orow + r4][ocol + 16] = acc11[r4];
    }
    __syncthreads();

    if (tid < 32 * 16) {
        int ch2 = tid & 15;
        int r_  = tid >> 4;               // 0..31
        float c0 = 0.f, c1 = 0.f;
        #pragma unroll
        for (int ww = 0; ww < 16; ++ww) {
            c0 += red[ww][r_][2 * ch2];
            c1 += red[ww][r_][2 * ch2 + 1];
        }
        int n_ = mb * 32 + r_;
        coup[(size_t)n_ * NBC + 2 * ch2]     = c0;
        coup[(size_t)n_ * NBC + 2 * ch2 + 1] = c1;
    }
}

// ---------------- oscillator update: reads coup, updates Xbf IN PLACE (proven-safe handoff) ----------------
__global__ void update_coup_k(const float* __restrict__ coup, const float* __restrict__ y_arr,
                              const float* __restrict__ omg, const float* __restrict__ gamma,
                              float* __restrict__ x0f, __bf16* __restrict__ Xbf,
                              float* __restrict__ out_k) {
    int tid = blockIdx.x * 256 + threadIdx.x;   // 131072
    int pi = tid & 15;
    int b = pi >> 3, j = pi & 7;
    int n = tid >> 4;
    int base = n * NBC + b * NC + 2 * j;
    float c0 = coup[base];
    float c1 = coup[base + 1];
    float y0 = y_arr[base] + c0;
    float y1 = y_arr[base + 1] + c1;
    size_t xi = ((size_t)(b * NN + n)) * NC + 2 * j;
    float x0 = x0f[xi], x1 = x0f[xi + 1];
    float sim = x0 * y0 + x1 * y1;
    float p0 = y0 - sim * x0;
    float p1 = y1 - sim * x1;
    float om = fabsf(omg[j]);
    float g  = gamma[0];
    float v0 = x0 + g * ( om * x1 + p0);
    float v1 = x1 + g * (-om * x0 + p1);
    float inv = 1.f / (sqrtf(v0*v0 + v1*v1) + 1e-6f);
    v0 *= inv; v1 *= inv;
    out_k[xi] = v0; out_k[xi + 1] = v1;
    x0f[xi] = v0; x0f[xi + 1] = v1;
    Xbf[(size_t)(b*NC + 2*j)     * NN + n] = (__bf16)v0;
    Xbf[(size_t)(b*NC + 2*j + 1) * NN + n] = (__bf16)v1;
}

// ---------------- fallback path (workspace too small): fused sc*cw gemm + KS update ----------------
__device__ inline bf16x8 mulcvt8(const float* __restrict__ s, const float* __restrict__ w) {
    f32x4 s0 = ((const f32x4*)s)[0], s1 = ((const f32x4*)s)[1];
    f32x4 w0 = ((const f32x4*)w)[0], w1 = ((const f32x4*)w)[1];
    return cvt8(s0, s1, w0, w1);
}

__global__ __launch_bounds__(256) void gemm_step_fused_k(const float* __restrict__ sc,
                                                         const float* __restrict__ cw,
                                                         const __bf16* __restrict__ Xbf,
                                                         float* __restrict__ part) {
    int mb = blockIdx.x;
    int ks = blockIdx.y;
    int lane = threadIdx.x & 63;
    int w = threadIdx.x >> 6;
    int row = mb * 64 + w * 16 + (lane & 15);
    int kb  = (lane >> 4) * 8;
    int k0  = ks * (NN / KS);
    const int KC = NN / KS;
    f32x4 acc0 = {0.f,0.f,0.f,0.f}, acc1 = {0.f,0.f,0.f,0.f};
    const __bf16* bp0 = Xbf + (size_t)(lane & 15) * NN + k0 + kb;
    const __bf16* bp1 = bp0 + (size_t)16 * NN;
    const float* as = sc + (size_t)row * NN + k0 + kb;
    const float* aw = cw + (size_t)row * NN + k0 + kb;
    #pragma unroll 4
    for (int k = 0; k < KC; k += 32) {
        bf16x8 a  = mulcvt8(as + k, aw + k);
        bf16x8 b0 = *(const bf16x8*)(bp0 + k);
        bf16x8 b1 = *(const bf16x8*)(bp1 + k);
        acc0 = __builtin_amdgcn_mfma_f32_16x16x32_bf16(a, b0, acc0, 0, 0, 0);
        acc1 = __builtin_amdgcn_mfma_f32_16x16x32_bf16(a, b1, acc1, 0, 0, 0);
    }
    int orow = mb * 64 + w * 16 + (lane >> 4) * 4;
    int ocol = lane & 15;
    float* pp = part + (size_t)ks * NN * NBC + (size_t)orow * NBC + ocol;
    #pragma unroll
    for (int r = 0; r < 4; ++r) {
        pp[(size_t)r * NBC]      = acc0[r];
        pp[(size_t)r * NBC + 16] = acc1[r];
    }
}

__global__ void update_step_k(const float* __restrict__ part, const float* __restrict__ y_arr,
                              const float* __restrict__ omg, const float* __restrict__ gamma,
                              float* __restrict__ x0f, __bf16* __restrict__ Xbf,
                              float* __restrict__ out_k) {
    int tid = blockIdx.x * 256 + threadIdx.x;   // 131072
    int pi = tid & 15;
    int b = pi >> 3, j = pi & 7;
    int n = tid >> 4;
    int base = n * NBC + b * NC + 2 * j;
    float c0 = 0.f, c1 = 0.f;
    #pragma unroll
    for (int ks = 0; ks < KS; ++ks) {
        const float* p = part + (size_t)ks * NN * NBC + base;
        c0 += p[0]; c1 += p[1];
    }
    float y0 = y_arr[base] + c0;
    float y1 = y_arr[base + 1] + c1;
    size_t xi = ((size_t)(b * NN + n)) * NC + 2 * j;
    float x0 = x0f[xi], x1 = x0f[xi + 1];
    float sim = x0 * y0 + x1 * y1;
    float p0 = y0 - sim * x0;
    float p1 = y1 - sim * x1;
    float om = fabsf(omg[j]);
    float g  = gamma[0];
    float v0 = x0 + g * ( om * x1 + p0);
    float v1 = x1 + g * (-om * x0 + p1);
    float inv = 1.f / (sqrtf(v0*v0 + v1*v1) + 1e-6f);
    v0 *= inv; v1 *= inv;
    out_k[xi] = v0; out_k[xi + 1] = v1;
    x0f[xi] = v0; x0f[xi + 1] = v1;
    Xbf[(size_t)(b*NC + 2*j)     * NN + n] = (__bf16)v0;
    Xbf[(size_t)(b*NC + 2*j + 1) * NN + n] = (__bf16)v1;
}

extern "C" void kernel_launch(void* const* d_in, const int* in_sizes, int n_in,
                              void* d_out, int out_size, void* d_ws, size_t ws_size,
                              hipStream_t stream) {
    const float* x     = (const float*)d_in[0];
    const float* c     = (const float*)d_in[1];
    const float* sc    = (const float*)d_in[2];
    const float* gnw   = (const float*)d_in[3];
    const float* gnb   = (const float*)d_in[4];
    const float* cw    = (const float*)d_in[5];
    const float* omg   = (const float*)d_in[6];
    const float* gamma = (const float*)d_in[7];
    float* out = (float*)d_out;
    int Q = out_size / STEP_ELEMS;

    const size_t szA    = (size_t)NN * NN * 2;        // 128 MiB
    const size_t szX    = (size_t)NBC * NN * 2;       // 512 KiB
    const size_t szX0f  = (size_t)NB * NN * NC * 4;   // 1 MiB
    const size_t szY    = (size_t)NN * NBC * 4;       // 1 MiB
    const size_t szCoup = (size_t)NN * NBC * 4;       // 1 MiB
    const size_t szPart = (size_t)KS * NN * NBC * 4;  // 16 MiB (fallback only)
    const size_t rest = szX + szX0f + szY + szCoup + szPart + 256;
    bool bigws = ws_size >= szA + rest;

    char* p = (char*)d_ws;
    __bf16* Af = nullptr;
    if (bigws) { Af = (__bf16*)p; p += szA; }
    __bf16* Xbf  = (__bf16*)p; p += szX;
    float* x0f   = (float*)p;  p += szX0f;
    float* y_arr = (float*)p;  p += szY;
    float* coup  = (float*)p;  p += szCoup;
    float* part  = (float*)p;  p += szPart;
    float* stats = (float*)p;  p += 256;

    gn_stats_k<<<16, 256, 0, stream>>>(c, stats);
    prep_xy_k<<<(NB * NN * 8) / 256, 256, 0, stream>>>(x, c, gnw, gnb, stats, y_arr, x0f, Xbf);

    if (bigws) {
        prep_A_frag_k<<<(NN / 16) * (NN / 512), 256, 0, stream>>>(sc, cw, Af);
        for (int q = 0; q < Q; ++q) {
            gemm_frag_k<<<NN / 32, 1024, 0, stream>>>(Af, Xbf, coup);
            update_coup_k<<<(NB * NN * 8) / 256, 256, 0, stream>>>(
                coup, y_arr, omg, gamma, x0f, Xbf, out + (size_t)q * STEP_ELEMS);
        }
    } else {
        dim3 gg(NN / 64, KS);
        for (int q = 0; q < Q; ++q) {
            gemm_step_fused_k<<<gg, 256, 0, stream>>>(sc, cw, Xbf, part);
            update_step_k<<<(NB * NN * 8) / 256, 256, 0, stream>>>(
                part, y_arr, omg, gamma, x0f, Xbf, out + (size_t)q * STEP_ELEMS);
        }
    }
}